// Round 1
// baseline (1411.965 us; speedup 1.0000x reference)
//
#include <hip/hip_runtime.h>
#include <math.h>

// ANI per-type MLP ensemble, MI355X fp32 baseline.
// Atoms binned by species type, then one VALU-bound MLP kernel:
//   lane = atom (64 atoms/block), wave = output-column chunk,
//   weights via wave-uniform scalar loads, x via conflict-free LDS reads.

#define NATOMS   131072                     // 2048 * 64
#define NMOL     2048
#define AEV      384
#define NTYPES   4
#define MBLK     64                         // atoms per MLP block
#define PADTOT   (NATOMS + NTYPES * MBLK)   // 131328 (type buckets padded to 64)
#define NBLK_MLP (PADTOT / MBLK)            // 2052

__device__ __forceinline__ float celu01(float v) {
  // jax.nn.celu, alpha = 0.1
  return (v > 0.f) ? v : 0.1f * (expf(v * 10.f) - 1.f);
}

// ---- binning pass -----------------------------------------------------------

__global__ void k_init(const int* __restrict__ species, float* __restrict__ out,
                       int* __restrict__ counts, int* __restrict__ perm) {
  const int i = blockIdx.x * 256 + threadIdx.x;   // grid covers PADTOT exactly
  if (i < 8) counts[i] = 0;
  perm[i] = -1;
  if (i < NATOMS) out[i] = (float)species[i];     // output 0: species passthrough
  if (i < NMOL) out[NATOMS + i] = 0.f;            // output 1: energies (accumulated)
}

__global__ void k_rank(const int* __restrict__ species, int* counts,
                       int* __restrict__ rank) {
  const int i = blockIdx.x * 256 + threadIdx.x;   // grid covers NATOMS exactly
  rank[i] = atomicAdd(&counts[species[i]], 1);
}

__global__ void k_scan(const int* __restrict__ counts, int* __restrict__ poff) {
  if (threadIdx.x == 0) {
    int acc = 0;
    poff[0] = 0;
    for (int t = 0; t < NTYPES; ++t) {
      acc += (counts[t] + MBLK - 1) / MBLK * MBLK;  // pad each bucket to 64
      poff[t + 1] = acc;
    }
  }
}

__global__ void k_scatter(const int* __restrict__ species, const int* __restrict__ rank,
                          const int* __restrict__ poff, int* __restrict__ perm) {
  const int i = blockIdx.x * 256 + threadIdx.x;
  perm[poff[species[i]] + rank[i]] = i;
}

// ---- fused 4-layer MLP + molecule reduction ---------------------------------
// Block: 256 threads = 4 waves, 64 atoms. lane == atom-within-block.
// Wave w owns output columns [w*N/4, (w+1)*N/4); weight addresses are
// wave-uniform (readfirstlane) so the compiler emits scalar loads.
// x values come from LDS with stride 65/41 (odd) -> 2-way bank alias = free.

__global__ __launch_bounds__(256, 2) void k_mlp(
    const float* __restrict__ aev,
    const float* __restrict__ W0, const float* __restrict__ b0,
    const float* __restrict__ W1, const float* __restrict__ b1,
    const float* __restrict__ W2, const float* __restrict__ b2,
    const float* __restrict__ W3, const float* __restrict__ b3,
    const int* __restrict__ poff, const int* __restrict__ perm,
    float* __restrict__ outE)
{
  __shared__ float XA[64 * 65];   // aev slice staging: 64 atoms x 64 cols (+1 pad)
  __shared__ float XB[64 * 41];   // inter-layer chunk buffer: <=40 cols (+1 pad)
  __shared__ float red[4 * 64];   // layer-3 cross-wave reduction

  const int tid   = threadIdx.x;
  const int lane  = tid & 63;                              // atom index in block
  const int wv    = __builtin_amdgcn_readfirstlane(tid >> 6);
  const int slot0 = blockIdx.x * MBLK;

  int t_ = (slot0 >= poff[1]) + (slot0 >= poff[2]) + (slot0 >= poff[3]);
  if (t_ > 3) t_ = 3;
  const int t = __builtin_amdgcn_readfirstlane(t_);

  // ---------------- layer 0: 384 -> 160 (x staged in 6 slices of 64) --------
  const int nb0 = __builtin_amdgcn_readfirstlane(wv * 40);
  float acc0[40];
  {
    const float* B = b0 + t * 160;
#pragma unroll
    for (int j = 0; j < 40; ++j) acc0[j] = B[nb0 + j];
  }
  const float* W0t = W0 + (size_t)t * AEV * 160;
  for (int s = 0; s < 6; ++s) {
    for (int idx = tid; idx < 64 * 64; idx += 256) {
      const int m = idx >> 6, k = idx & 63;
      const int ai = perm[slot0 + m];
      XA[m * 65 + k] = (ai >= 0) ? aev[(size_t)ai * AEV + s * 64 + k] : 0.f;
    }
    __syncthreads();
    for (int kk = 0; kk < 64; ++kk) {
      const float xk = XA[lane * 65 + kk];
      const float* wr = W0t + (size_t)(s * 64 + kk) * 160 + nb0;
#pragma unroll
      for (int j = 0; j < 40; ++j) acc0[j] = fmaf(xk, wr[j], acc0[j]);
    }
    __syncthreads();
  }
#pragma unroll
  for (int j = 0; j < 40; ++j) acc0[j] = celu01(acc0[j]);

  // ---------------- layer 1: 160 -> 128 (h0 chunks of 40 via XB) ------------
  const int nb1 = __builtin_amdgcn_readfirstlane(wv * 32);
  float acc1[32];
  {
    const float* B = b1 + t * 128;
#pragma unroll
    for (int j = 0; j < 32; ++j) acc1[j] = B[nb1 + j];
  }
  const float* W1t = W1 + (size_t)t * 160 * 128;
  for (int c = 0; c < 4; ++c) {
    if (wv == c) {
#pragma unroll
      for (int j = 0; j < 40; ++j) XB[lane * 41 + j] = acc0[j];
    }
    __syncthreads();
    for (int q = 0; q < 40; ++q) {
      const float xk = XB[lane * 41 + q];
      const float* wr = W1t + (size_t)(c * 40 + q) * 128 + nb1;
#pragma unroll
      for (int j = 0; j < 32; ++j) acc1[j] = fmaf(xk, wr[j], acc1[j]);
    }
    __syncthreads();
  }
#pragma unroll
  for (int j = 0; j < 32; ++j) acc1[j] = celu01(acc1[j]);

  // ---------------- layer 2: 128 -> 96 (h1 chunks of 32 via XB) -------------
  const int nb2 = __builtin_amdgcn_readfirstlane(wv * 24);
  float acc2[24];
  {
    const float* B = b2 + t * 96;
#pragma unroll
    for (int j = 0; j < 24; ++j) acc2[j] = B[nb2 + j];
  }
  const float* W2t = W2 + (size_t)t * 128 * 96;
  for (int c = 0; c < 4; ++c) {
    if (wv == c) {
#pragma unroll
      for (int j = 0; j < 32; ++j) XB[lane * 41 + j] = acc1[j];
    }
    __syncthreads();
    for (int q = 0; q < 32; ++q) {
      const float xk = XB[lane * 41 + q];
      const float* wr = W2t + (size_t)(c * 32 + q) * 96 + nb2;
#pragma unroll
      for (int j = 0; j < 24; ++j) acc2[j] = fmaf(xk, wr[j], acc2[j]);
    }
    __syncthreads();
  }

  // ---------------- layer 3: 96 -> 1 (straight from registers) --------------
  const float* w3 = W3 + t * 96;
  float part = 0.f;
#pragma unroll
  for (int q = 0; q < 24; ++q) part = fmaf(celu01(acc2[q]), w3[nb2 + q], part);
  red[wv * 64 + lane] = part;
  __syncthreads();
  if (wv == 0) {
    const float e = red[lane] + red[64 + lane] + red[128 + lane] + red[192 + lane] + b3[t];
    const int ai = perm[slot0 + lane];
    if (ai >= 0) atomicAdd(&outE[ai >> 6], e);   // molecule = atom_index / 64
  }
}

// ---- launch -----------------------------------------------------------------

extern "C" void kernel_launch(void* const* d_in, const int* in_sizes, int n_in,
                              void* d_out, int out_size, void* d_ws, size_t ws_size,
                              hipStream_t stream)
{
  const int*   species = (const int*)d_in[0];
  const float* aev     = (const float*)d_in[1];
  const float* W0 = (const float*)d_in[2];
  const float* b0 = (const float*)d_in[3];
  const float* W1 = (const float*)d_in[4];
  const float* b1 = (const float*)d_in[5];
  const float* W2 = (const float*)d_in[6];
  const float* b2 = (const float*)d_in[7];
  const float* W3 = (const float*)d_in[8];
  const float* b3 = (const float*)d_in[9];
  float* out = (float*)d_out;

  // workspace layout (ints): [0..7] counts, [8..15] poff, rank[NATOMS], perm[PADTOT]
  int* counts = (int*)d_ws;
  int* poff   = counts + 8;
  int* rank   = counts + 16;
  int* perm   = rank + NATOMS;

  k_init   <<<PADTOT / 256, 256, 0, stream>>>(species, out, counts, perm);
  k_rank   <<<NATOMS / 256, 256, 0, stream>>>(species, counts, rank);
  k_scan   <<<1, 64, 0, stream>>>(counts, poff);
  k_scatter<<<NATOMS / 256, 256, 0, stream>>>(species, rank, poff, perm);
  k_mlp    <<<NBLK_MLP, 256, 0, stream>>>(aev, W0, b0, W1, b1, W2, b2, W3, b3,
                                          poff, perm, out + NATOMS);
}

// Round 2
// 623.524 us; speedup vs baseline: 2.2645x; 2.2645x over previous
//
#include <hip/hip_runtime.h>
#include <math.h>

// ANI per-type MLP ensemble, MI355X fp32.
// R2: atomic-free counting sort (ballot/mbcnt) replaces the 705us k_rank
//     (131k atomics on 4 addresses); float4 aev staging in k_mlp.

#define NATOMS   131072                     // 2048 * 64
#define NMOL     2048
#define AEV      384
#define NTYPES   4
#define MBLK     64                         // atoms per MLP block
#define PADTOT   (NATOMS + NTYPES * MBLK)   // 131328 (type buckets padded to 64)
#define NBLK_MLP (PADTOT / MBLK)            // 2052
#define NBLK_H   512                        // histogram blocks (256 atoms each)

__device__ __forceinline__ float celu01(float v) {
  // jax.nn.celu, alpha = 0.1
  return (v > 0.f) ? v : 0.1f * (expf(v * 10.f) - 1.f);
}

// ---- binning pass (atomic-free counting sort) -------------------------------

__global__ void k_init(const int* __restrict__ species, float* __restrict__ out,
                       int* __restrict__ perm) {
  const int i = blockIdx.x * 256 + threadIdx.x;   // grid covers PADTOT exactly
  perm[i] = -1;
  if (i < NATOMS) out[i] = (float)species[i];     // output 0: species passthrough
  if (i < NMOL) out[NATOMS + i] = 0.f;            // output 1: energies (accumulated)
}

__global__ void k_hist(const int* __restrict__ species, int* __restrict__ hist) {
  const int tid = threadIdx.x, blk = blockIdx.x;
  const int sp = species[blk * 256 + tid];
  const int wv = tid >> 6;
  __shared__ int wc[4 * NTYPES];                  // [wave][type]
#pragma unroll
  for (int t = 0; t < NTYPES; ++t) {
    const unsigned long long m = __ballot(sp == t);
    if ((tid & 63) == 0) wc[wv * NTYPES + t] = __popcll(m);
  }
  __syncthreads();
  if (tid < NTYPES)
    hist[tid * NBLK_H + blk] = wc[tid] + wc[4 + tid] + wc[8 + tid] + wc[12 + tid];
}

// one block, 256 threads: wave t owns type t
__global__ void k_scan(const int* __restrict__ hist, int* __restrict__ poff,
                       int* __restrict__ boff) {
  __shared__ int tot[NTYPES], base[NTYPES];
  const int tid = threadIdx.x, wv = tid >> 6, lane = tid & 63;

  int s = 0;                                      // per-type total
  for (int c = 0; c < 8; ++c) s += hist[wv * NBLK_H + c * 64 + lane];
  for (int off = 32; off; off >>= 1) s += __shfl_down(s, off);
  if (lane == 0) tot[wv] = s;
  __syncthreads();

  if (tid == 0) {                                 // padded type bases
    int acc = 0; poff[0] = 0;
    for (int t = 0; t < NTYPES; ++t) {
      base[t] = acc;
      acc += ((tot[t] + 63) >> 6) << 6;
      poff[t + 1] = acc;
    }
  }
  __syncthreads();

  int carry = base[wv];                           // exclusive scan over blocks
  for (int c = 0; c < 8; ++c) {
    const int orig = hist[wv * NBLK_H + c * 64 + lane];
    int v = orig;
    for (int off = 1; off < 64; off <<= 1) {
      const int u = __shfl_up(v, off);
      if (lane >= off) v += u;
    }
    boff[wv * NBLK_H + c * 64 + lane] = carry + v - orig;
    carry += __shfl(v, 63);
  }
}

__global__ void k_scatter(const int* __restrict__ species, const int* __restrict__ boff,
                          int* __restrict__ perm) {
  const int tid = threadIdx.x, blk = blockIdx.x;
  const int i = blk * 256 + tid;
  const int sp = species[i];
  const int wv = tid >> 6;
  __shared__ int wc[4 * NTYPES];
  unsigned long long msel = 0;
#pragma unroll
  for (int t = 0; t < NTYPES; ++t) {
    const unsigned long long m = __ballot(sp == t);
    if ((tid & 63) == 0) wc[wv * NTYPES + t] = __popcll(m);
    if (sp == t) msel = m;
  }
  __syncthreads();
  int woff = 0;
  for (int w = 0; w < wv; ++w) woff += wc[w * NTYPES + sp];
  const int rk = __builtin_amdgcn_mbcnt_hi((unsigned)(msel >> 32),
                 __builtin_amdgcn_mbcnt_lo((unsigned)msel, 0));
  perm[boff[sp * NBLK_H + blk] + woff + rk] = i;
}

// ---- fused 4-layer MLP + molecule reduction ---------------------------------
// Block: 256 threads = 4 waves, 64 atoms. lane == atom-within-block.
// Wave w owns output columns [w*N/4, (w+1)*N/4); weight addresses are
// wave-uniform (readfirstlane) so the compiler emits scalar loads.
// x values come from LDS with stride 65/41 (odd) -> 2-way bank alias = free.

__global__ __launch_bounds__(256, 2) void k_mlp(
    const float* __restrict__ aev,
    const float* __restrict__ W0, const float* __restrict__ b0,
    const float* __restrict__ W1, const float* __restrict__ b1,
    const float* __restrict__ W2, const float* __restrict__ b2,
    const float* __restrict__ W3, const float* __restrict__ b3,
    const int* __restrict__ poff, const int* __restrict__ perm,
    float* __restrict__ outE)
{
  __shared__ float XA[64 * 65];   // aev slice staging: 64 atoms x 64 cols (+1 pad)
  __shared__ float XB[64 * 41];   // inter-layer chunk buffer: <=40 cols (+1 pad)
  __shared__ float red[4 * 64];   // layer-3 cross-wave reduction
  __shared__ int   permS[64];

  const int tid   = threadIdx.x;
  const int lane  = tid & 63;                              // atom index in block
  const int wv    = __builtin_amdgcn_readfirstlane(tid >> 6);
  const int slot0 = blockIdx.x * MBLK;

  if (tid < 64) permS[tid] = perm[slot0 + tid];

  int t_ = (slot0 >= poff[1]) + (slot0 >= poff[2]) + (slot0 >= poff[3]);
  if (t_ > 3) t_ = 3;
  const int t = __builtin_amdgcn_readfirstlane(t_);
  __syncthreads();

  // ---------------- layer 0: 384 -> 160 (x staged in 6 slices of 64) --------
  const int nb0 = __builtin_amdgcn_readfirstlane(wv * 40);
  float acc0[40];
  {
    const float* B = b0 + t * 160;
#pragma unroll
    for (int j = 0; j < 40; ++j) acc0[j] = B[nb0 + j];
  }
  const float* W0t = W0 + (size_t)t * AEV * 160;
  for (int s = 0; s < 6; ++s) {
    for (int idx = tid; idx < 64 * 16; idx += 256) {      // float4 per thread
      const int m = idx >> 4, k4 = (idx & 15) * 4;
      const int ai = permS[m];
      float4 v = make_float4(0.f, 0.f, 0.f, 0.f);
      if (ai >= 0) v = *(const float4*)(aev + (size_t)ai * AEV + s * 64 + k4);
      XA[m * 65 + k4 + 0] = v.x;
      XA[m * 65 + k4 + 1] = v.y;
      XA[m * 65 + k4 + 2] = v.z;
      XA[m * 65 + k4 + 3] = v.w;
    }
    __syncthreads();
    for (int kk = 0; kk < 64; ++kk) {
      const float xk = XA[lane * 65 + kk];
      const float* wr = W0t + (size_t)(s * 64 + kk) * 160 + nb0;
#pragma unroll
      for (int j = 0; j < 40; ++j) acc0[j] = fmaf(xk, wr[j], acc0[j]);
    }
    __syncthreads();
  }
#pragma unroll
  for (int j = 0; j < 40; ++j) acc0[j] = celu01(acc0[j]);

  // ---------------- layer 1: 160 -> 128 (h0 chunks of 40 via XB) ------------
  const int nb1 = __builtin_amdgcn_readfirstlane(wv * 32);
  float acc1[32];
  {
    const float* B = b1 + t * 128;
#pragma unroll
    for (int j = 0; j < 32; ++j) acc1[j] = B[nb1 + j];
  }
  const float* W1t = W1 + (size_t)t * 160 * 128;
  for (int c = 0; c < 4; ++c) {
    if (wv == c) {
#pragma unroll
      for (int j = 0; j < 40; ++j) XB[lane * 41 + j] = acc0[j];
    }
    __syncthreads();
    for (int q = 0; q < 40; ++q) {
      const float xk = XB[lane * 41 + q];
      const float* wr = W1t + (size_t)(c * 40 + q) * 128 + nb1;
#pragma unroll
      for (int j = 0; j < 32; ++j) acc1[j] = fmaf(xk, wr[j], acc1[j]);
    }
    __syncthreads();
  }
#pragma unroll
  for (int j = 0; j < 32; ++j) acc1[j] = celu01(acc1[j]);

  // ---------------- layer 2: 128 -> 96 (h1 chunks of 32 via XB) -------------
  const int nb2 = __builtin_amdgcn_readfirstlane(wv * 24);
  float acc2[24];
  {
    const float* B = b2 + t * 96;
#pragma unroll
    for (int j = 0; j < 24; ++j) acc2[j] = B[nb2 + j];
  }
  const float* W2t = W2 + (size_t)t * 128 * 96;
  for (int c = 0; c < 4; ++c) {
    if (wv == c) {
#pragma unroll
      for (int j = 0; j < 32; ++j) XB[lane * 41 + j] = acc1[j];
    }
    __syncthreads();
    for (int q = 0; q < 32; ++q) {
      const float xk = XB[lane * 41 + q];
      const float* wr = W2t + (size_t)(c * 32 + q) * 96 + nb2;
#pragma unroll
      for (int j = 0; j < 24; ++j) acc2[j] = fmaf(xk, wr[j], acc2[j]);
    }
    __syncthreads();
  }

  // ---------------- layer 3: 96 -> 1 (straight from registers) --------------
  const float* w3 = W3 + t * 96;
  float part = 0.f;
#pragma unroll
  for (int q = 0; q < 24; ++q) part = fmaf(celu01(acc2[q]), w3[nb2 + q], part);
  red[wv * 64 + lane] = part;
  __syncthreads();
  if (wv == 0) {
    const float e = red[lane] + red[64 + lane] + red[128 + lane] + red[192 + lane] + b3[t];
    const int ai = permS[lane];
    if (ai >= 0) atomicAdd(&outE[ai >> 6], e);   // molecule = atom_index / 64
  }
}

// ---- launch -----------------------------------------------------------------

extern "C" void kernel_launch(void* const* d_in, const int* in_sizes, int n_in,
                              void* d_out, int out_size, void* d_ws, size_t ws_size,
                              hipStream_t stream)
{
  const int*   species = (const int*)d_in[0];
  const float* aev     = (const float*)d_in[1];
  const float* W0 = (const float*)d_in[2];
  const float* b0 = (const float*)d_in[3];
  const float* W1 = (const float*)d_in[4];
  const float* b1 = (const float*)d_in[5];
  const float* W2 = (const float*)d_in[6];
  const float* b2 = (const float*)d_in[7];
  const float* W3 = (const float*)d_in[8];
  const float* b3 = (const float*)d_in[9];
  float* out = (float*)d_out;

  // workspace layout (ints): poff[8], hist[4*512], boff[4*512], perm[PADTOT]
  int* poff = (int*)d_ws;
  int* hist = poff + 8;
  int* boff = hist + NTYPES * NBLK_H;
  int* perm = boff + NTYPES * NBLK_H;

  k_init   <<<PADTOT / 256, 256, 0, stream>>>(species, out, perm);
  k_hist   <<<NBLK_H, 256, 0, stream>>>(species, hist);
  k_scan   <<<1, 256, 0, stream>>>(hist, poff, boff);
  k_scatter<<<NBLK_H, 256, 0, stream>>>(species, boff, perm);
  k_mlp    <<<NBLK_MLP, 256, 0, stream>>>(aev, W0, b0, W1, b1, W2, b2, W3, b3,
                                          poff, perm, out + NATOMS);
}

// Round 3
// 386.407 us; speedup vs baseline: 3.6541x; 1.6136x over previous
//
#include <hip/hip_runtime.h>
#include <math.h>

// ANI per-type MLP ensemble, MI355X.
// R3: bf16 MFMA (16x16x32) replaces the fp32 VALU MLP (which was stalling at
//     VALUBusy=49% on the scalar weight stream and capped at the 157us fp32
//     wall). Weights pre-swizzled once into B-fragment-linear bf16 in d_ws;
//     activations staged/repacked through LDS in bf16; fp32 accumulation.

#define NATOMS   131072                     // 2048 * 64
#define NMOL     2048
#define AEV      384
#define NTYPES   4
#define MBLK     64                         // atoms per MLP block
#define PADTOT   (NATOMS + NTYPES * MBLK)   // 131328
#define NBLK_MLP (PADTOT / MBLK)            // 2052
#define NBLK_H   512                        // histogram blocks (256 atoms each)

// swizzled-weight layout (bf16, per type): L0 [12kt][10nt][64][8] = 61440,
// L1 [5][8][64][8] = 20480, L2 [4][6][64][8] = 12288  -> 94208 per type
#define WB_L1 61440
#define WB_L2 81920
#define WB_T  94208

typedef __attribute__((ext_vector_type(8))) short bf16x8;
typedef __attribute__((ext_vector_type(4))) float f32x4;

__device__ __forceinline__ float celu01(float v) {
  return (v > 0.f) ? v : 0.1f * (expf(v * 10.f) - 1.f);   // jax.nn.celu alpha=0.1
}
__device__ __forceinline__ unsigned short f2bf(float x) {  // RNE
  unsigned u = __float_as_uint(x);
  return (unsigned short)((u + 0x7FFFu + ((u >> 16) & 1u)) >> 16);
}
__device__ __forceinline__ float bf2f(unsigned short h) {
  return __uint_as_float(((unsigned)h) << 16);
}

// ---- binning pass (atomic-free counting sort) -------------------------------

__global__ void k_init(const int* __restrict__ species, float* __restrict__ out,
                       int* __restrict__ perm) {
  const int i = blockIdx.x * 256 + threadIdx.x;   // grid covers PADTOT exactly
  perm[i] = -1;
  if (i < NATOMS) out[i] = (float)species[i];
  if (i < NMOL) out[NATOMS + i] = 0.f;
}

__global__ void k_hist(const int* __restrict__ species, int* __restrict__ hist) {
  const int tid = threadIdx.x, blk = blockIdx.x;
  const int sp = species[blk * 256 + tid];
  const int wv = tid >> 6;
  __shared__ int wc[4 * NTYPES];
#pragma unroll
  for (int t = 0; t < NTYPES; ++t) {
    const unsigned long long m = __ballot(sp == t);
    if ((tid & 63) == 0) wc[wv * NTYPES + t] = __popcll(m);
  }
  __syncthreads();
  if (tid < NTYPES)
    hist[tid * NBLK_H + blk] = wc[tid] + wc[4 + tid] + wc[8 + tid] + wc[12 + tid];
}

__global__ void k_scan(const int* __restrict__ hist, int* __restrict__ poff,
                       int* __restrict__ boff) {
  __shared__ int tot[NTYPES], base[NTYPES];
  const int tid = threadIdx.x, wv = tid >> 6, lane = tid & 63;
  int s = 0;
  for (int c = 0; c < 8; ++c) s += hist[wv * NBLK_H + c * 64 + lane];
  for (int off = 32; off; off >>= 1) s += __shfl_down(s, off);
  if (lane == 0) tot[wv] = s;
  __syncthreads();
  if (tid == 0) {
    int acc = 0; poff[0] = 0;
    for (int t = 0; t < NTYPES; ++t) {
      base[t] = acc;
      acc += ((tot[t] + 63) >> 6) << 6;
      poff[t + 1] = acc;
    }
  }
  __syncthreads();
  int carry = base[wv];
  for (int c = 0; c < 8; ++c) {
    const int orig = hist[wv * NBLK_H + c * 64 + lane];
    int v = orig;
    for (int off = 1; off < 64; off <<= 1) {
      const int u = __shfl_up(v, off);
      if (lane >= off) v += u;
    }
    boff[wv * NBLK_H + c * 64 + lane] = carry + v - orig;
    carry += __shfl(v, 63);
  }
}

__global__ void k_scatter(const int* __restrict__ species, const int* __restrict__ boff,
                          int* __restrict__ perm) {
  const int tid = threadIdx.x, blk = blockIdx.x;
  const int i = blk * 256 + tid;
  const int sp = species[i];
  const int wv = tid >> 6;
  __shared__ int wc[4 * NTYPES];
  unsigned long long msel = 0;
#pragma unroll
  for (int t = 0; t < NTYPES; ++t) {
    const unsigned long long m = __ballot(sp == t);
    if ((tid & 63) == 0) wc[wv * NTYPES + t] = __popcll(m);
    if (sp == t) msel = m;
  }
  __syncthreads();
  int woff = 0;
  for (int w = 0; w < wv; ++w) woff += wc[w * NTYPES + sp];
  const int rk = __builtin_amdgcn_mbcnt_hi((unsigned)(msel >> 32),
                 __builtin_amdgcn_mbcnt_lo((unsigned)msel, 0));
  perm[boff[sp * NBLK_H + blk] + woff + rk] = i;
}

// ---- weight pre-swizzle: fp32 [K][N] -> bf16 B-fragment-linear --------------
// B-fragment (16x16x32): lane l holds B[k = kt*32 + (l>>4)*8 + j][n = nt*16 + (l&15)]

__global__ void k_wprep(const float* __restrict__ W0, const float* __restrict__ W1,
                        const float* __restrict__ W2, unsigned short* __restrict__ WB) {
  const int t = blockIdx.y;
  const int f = blockIdx.x * 256 + threadIdx.x;   // [0, WB_T), grid.x = 368
  int base, NT, N;
  const float* W;
  if (f < WB_L1)      { base = 0;     NT = 10; N = 160; W = W0 + (size_t)t * AEV * 160; }
  else if (f < WB_L2) { base = WB_L1; NT = 8;  N = 128; W = W1 + (size_t)t * 160 * 128; }
  else                { base = WB_L2; NT = 6;  N = 96;  W = W2 + (size_t)t * 128 * 96; }
  const int e = f - base, frag = e >> 9, r = e & 511, lane = r >> 3, j = r & 7;
  const int kt = frag / NT, nt = frag - kt * NT;
  const int k = kt * 32 + ((lane >> 4) << 3) + j, n = nt * 16 + (lane & 15);
  WB[(size_t)t * WB_T + f] = f2bf(W[k * N + n]);
}

// ---- fused 4-layer MFMA MLP + molecule reduction ----------------------------
// 256 threads = 4 waves; wave w = M-tile of 16 atoms. A-frags from LDS
// (ds_read_b128, padded strides), B-frags 16B/lane linear from L2-resident WB.

__global__ __launch_bounds__(256, 3) void k_mlp(
    const float* __restrict__ aev, const unsigned short* __restrict__ WB,
    const float* __restrict__ b0, const float* __restrict__ b1,
    const float* __restrict__ b2, const float* __restrict__ b3,
    const float* __restrict__ W3,
    const int* __restrict__ poff, const int* __restrict__ perm,
    float* __restrict__ outE)
{
  // LDSA: X half-tile 64x(192+8) bf16 = 25600B, reused as H1 64x(128+8) = 17408B
  // LDSB: H0 64x(160+8) bf16 = 21504B, reused as H2 64x(96+8) = 13312B
  __shared__ __align__(16) unsigned short LDSA[64 * 200];
  __shared__ __align__(16) unsigned short LDSB[64 * 168];
  __shared__ float red[256];
  __shared__ int   permS[64];

  const int tid  = threadIdx.x;
  const int lane = tid & 63;
  const int wv   = __builtin_amdgcn_readfirstlane(tid >> 6);
  const int quad = lane >> 4, l15 = lane & 15;
  const int slot0 = blockIdx.x * MBLK;

  if (tid < 64) permS[tid] = perm[slot0 + tid];
  int t_ = (slot0 >= poff[1]) + (slot0 >= poff[2]) + (slot0 >= poff[3]);
  if (t_ > 3) t_ = 3;
  const int t = __builtin_amdgcn_readfirstlane(t_);
  __syncthreads();

  const bf16x8* wb0 = (const bf16x8*)(WB + (size_t)t * WB_T);
  const bf16x8* wb1 = (const bf16x8*)(WB + (size_t)t * WB_T + WB_L1);
  const bf16x8* wb2 = (const bf16x8*)(WB + (size_t)t * WB_T + WB_L2);

  // ---------------- layer 0: 384 -> 160 --------------------------------------
  f32x4 acc0[10];
#pragma unroll
  for (int nt = 0; nt < 10; ++nt) {
    const float b = b0[t * 160 + nt * 16 + l15];
    acc0[nt] = (f32x4){b, b, b, b};
  }
  const int sm = tid >> 2, scg = tid & 3;          // staging: 4 threads/atom
  const int sai = permS[sm];
  for (int h = 0; h < 2; ++h) {                    // two K-halves of 192
    const float4* src = (const float4*)(aev + (size_t)(sai < 0 ? 0 : sai) * AEV + h * 192);
#pragma unroll 4
    for (int i = 0; i < 12; ++i) {
      const int c4 = scg + i * 4;
      float4 v = make_float4(0.f, 0.f, 0.f, 0.f);
      if (sai >= 0) v = src[c4];
      ushort4 p = {f2bf(v.x), f2bf(v.y), f2bf(v.z), f2bf(v.w)};
      *(ushort4*)&LDSA[sm * 200 + c4 * 4] = p;
    }
    __syncthreads();
    const int arow = (wv * 16 + l15) * 200 + quad * 8;
    for (int ks = 0; ks < 6; ++ks) {
      const bf16x8 a = *(const bf16x8*)&LDSA[arow + ks * 32];
      const int ksg = h * 6 + ks;
#pragma unroll
      for (int nt = 0; nt < 10; ++nt)
        acc0[nt] = __builtin_amdgcn_mfma_f32_16x16x32_bf16(a, wb0[(ksg * 10 + nt) * 64 + lane], acc0[nt], 0, 0, 0);
    }
    __syncthreads();
  }
  {
    const int hrow0 = wv * 16 + quad * 4;
#pragma unroll
    for (int nt = 0; nt < 10; ++nt)
#pragma unroll
      for (int r = 0; r < 4; ++r)
        LDSB[(hrow0 + r) * 168 + nt * 16 + l15] = f2bf(celu01(acc0[nt][r]));
  }
  __syncthreads();

  // ---------------- layer 1: 160 -> 128 --------------------------------------
  f32x4 acc1[8];
#pragma unroll
  for (int nt = 0; nt < 8; ++nt) {
    const float b = b1[t * 128 + nt * 16 + l15];
    acc1[nt] = (f32x4){b, b, b, b};
  }
  {
    const int arow = (wv * 16 + l15) * 168 + quad * 8;
    for (int ks = 0; ks < 5; ++ks) {
      const bf16x8 a = *(const bf16x8*)&LDSB[arow + ks * 32];
#pragma unroll
      for (int nt = 0; nt < 8; ++nt)
        acc1[nt] = __builtin_amdgcn_mfma_f32_16x16x32_bf16(a, wb1[(ks * 8 + nt) * 64 + lane], acc1[nt], 0, 0, 0);
    }
  }
  __syncthreads();                                  // all H0 reads done
  {
    const int hrow0 = wv * 16 + quad * 4;
#pragma unroll
    for (int nt = 0; nt < 8; ++nt)
#pragma unroll
      for (int r = 0; r < 4; ++r)
        LDSA[(hrow0 + r) * 136 + nt * 16 + l15] = f2bf(celu01(acc1[nt][r]));
  }
  __syncthreads();

  // ---------------- layer 2: 128 -> 96 ---------------------------------------
  f32x4 acc2[6];
#pragma unroll
  for (int nt = 0; nt < 6; ++nt) {
    const float b = b2[t * 96 + nt * 16 + l15];
    acc2[nt] = (f32x4){b, b, b, b};
  }
  {
    const int arow = (wv * 16 + l15) * 136 + quad * 8;
    for (int ks = 0; ks < 4; ++ks) {
      const bf16x8 a = *(const bf16x8*)&LDSA[arow + ks * 32];
#pragma unroll
      for (int nt = 0; nt < 6; ++nt)
        acc2[nt] = __builtin_amdgcn_mfma_f32_16x16x32_bf16(a, wb2[(ks * 6 + nt) * 64 + lane], acc2[nt], 0, 0, 0);
    }
  }
  __syncthreads();                                  // all H1 reads done
  {
    const int hrow0 = wv * 16 + quad * 4;
#pragma unroll
    for (int nt = 0; nt < 6; ++nt)
#pragma unroll
      for (int r = 0; r < 4; ++r)
        LDSB[(hrow0 + r) * 104 + nt * 16 + l15] = f2bf(celu01(acc2[nt][r]));
  }
  __syncthreads();

  // ---------------- layer 3: 96 -> 1, molecule reduce ------------------------
  const float* w3 = W3 + t * 96;
  float part = 0.f;
#pragma unroll
  for (int q = 0; q < 24; ++q) {
    const int c = wv * 24 + q;
    part = fmaf(bf2f(LDSB[lane * 104 + c]), w3[c], part);
  }
  red[wv * 64 + lane] = part;
  __syncthreads();
  if (wv == 0) {
    const float e = red[lane] + red[64 + lane] + red[128 + lane] + red[192 + lane] + b3[t];
    const int ai = permS[lane];
    if (ai >= 0) atomicAdd(&outE[ai >> 6], e);
  }
}

// ---- launch -----------------------------------------------------------------

extern "C" void kernel_launch(void* const* d_in, const int* in_sizes, int n_in,
                              void* d_out, int out_size, void* d_ws, size_t ws_size,
                              hipStream_t stream)
{
  const int*   species = (const int*)d_in[0];
  const float* aev     = (const float*)d_in[1];
  const float* W0 = (const float*)d_in[2];
  const float* b0 = (const float*)d_in[3];
  const float* W1 = (const float*)d_in[4];
  const float* b1 = (const float*)d_in[5];
  const float* W2 = (const float*)d_in[6];
  const float* b2 = (const float*)d_in[7];
  const float* W3 = (const float*)d_in[8];
  const float* b3 = (const float*)d_in[9];
  float* out = (float*)d_out;

  // ws (ints): poff[8], hist[2048], boff[2048], perm[PADTOT]; then bf16 WB
  int* poff = (int*)d_ws;
  int* hist = poff + 8;
  int* boff = hist + NTYPES * NBLK_H;
  int* perm = boff + NTYPES * NBLK_H;
  unsigned short* WB = (unsigned short*)(perm + PADTOT);   // 16B-aligned offset

  k_wprep  <<<dim3(WB_T / 256, NTYPES), 256, 0, stream>>>(W0, W1, W2, WB);
  k_init   <<<PADTOT / 256, 256, 0, stream>>>(species, out, perm);
  k_hist   <<<NBLK_H, 256, 0, stream>>>(species, hist);
  k_scan   <<<1, 256, 0, stream>>>(hist, poff, boff);
  k_scatter<<<NBLK_H, 256, 0, stream>>>(species, boff, perm);
  k_mlp    <<<NBLK_MLP, 256, 0, stream>>>(aev, WB, b0, b1, b2, b3, W3,
                                          poff, perm, out + NATOMS);
}

// Round 4
// 383.976 us; speedup vs baseline: 3.6772x; 1.0063x over previous
//
#include <hip/hip_runtime.h>
#include <math.h>

// ANI per-type MLP ensemble, MI355X bf16-MFMA.
// R4: occupancy attack. Single reused LDS arena (X sliced 4x96 -> H0 -> H1 ->
//     H2) cuts LDS 48.6KB -> 22.8KB (3 -> ~7 blocks/CU); launch count 6 -> 4
//     (wprep+init+hist fused); __expf celu. MFMA structure unchanged from R3
//     (passed at absmax 0.0625 vs 0.3425 threshold).

#define NATOMS   131072                     // 2048 * 64
#define NMOL     2048
#define AEV      384
#define NTYPES   4
#define MBLK     64                         // atoms per MLP block
#define PADTOT   (NATOMS + NTYPES * MBLK)   // 131328
#define NBLK_MLP (PADTOT / MBLK)            // 2052
#define NBLK_H   512                        // histogram blocks (256 atoms each)

// swizzled-weight layout (bf16, per type): L0 [12kt][10nt][64][8] = 61440,
// L1 [5][8][64][8] = 20480, L2 [4][6][64][8] = 12288  -> 94208 per type
#define WB_L1 61440
#define WB_L2 81920
#define WB_T  94208

typedef __attribute__((ext_vector_type(8))) short bf16x8;
typedef __attribute__((ext_vector_type(4))) float f32x4;

__device__ __forceinline__ float celu01(float v) {
  return (v > 0.f) ? v : 0.1f * (__expf(v * 10.f) - 1.f);  // v<0 => exp arg <0, safe
}
__device__ __forceinline__ unsigned short f2bf(float x) {  // RNE
  unsigned u = __float_as_uint(x);
  return (unsigned short)((u + 0x7FFFu + ((u >> 16) & 1u)) >> 16);
}
__device__ __forceinline__ float bf2f(unsigned short h) {
  return __uint_as_float(((unsigned)h) << 16);
}

// ---- fused prep: out init + perm init + weight swizzle + histogram ----------

__global__ void k_pre(const int* __restrict__ species, float* __restrict__ out,
                      int* __restrict__ perm, int* __restrict__ hist,
                      const float* __restrict__ W0, const float* __restrict__ W1,
                      const float* __restrict__ W2, unsigned short* __restrict__ WB) {
  const int tid = threadIdx.x, blk = blockIdx.x;
  const int i = blk * 256 + tid;                  // grid = PADTOT/256 = 513
  perm[i] = -1;
  if (i < NATOMS) out[i] = (float)species[i];     // output 0: species passthrough
  if (i < NMOL) out[NATOMS + i] = 0.f;            // output 1: energies

  // weight swizzle, grid-stride over 4*WB_T elements
  for (int f = i; f < NTYPES * WB_T; f += PADTOT) {
    const int t = f / WB_T, e0 = f - t * WB_T;
    int base, NT, N;
    const float* W;
    if (e0 < WB_L1)      { base = 0;     NT = 10; N = 160; W = W0 + (size_t)t * AEV * 160; }
    else if (e0 < WB_L2) { base = WB_L1; NT = 8;  N = 128; W = W1 + (size_t)t * 160 * 128; }
    else                 { base = WB_L2; NT = 6;  N = 96;  W = W2 + (size_t)t * 128 * 96; }
    const int e = e0 - base, frag = e >> 9, r = e & 511, lane = r >> 3, j = r & 7;
    const int kt = frag / NT, nt = frag - kt * NT;
    const int k = kt * 32 + ((lane >> 4) << 3) + j, n = nt * 16 + (lane & 15);
    WB[(size_t)t * WB_T + e0] = f2bf(W[k * N + n]);
  }

  if (blk < NBLK_H) {                             // histogram (blocks 0..511)
    const int sp = species[i];
    const int wv = tid >> 6;
    __shared__ int wc[4 * NTYPES];
#pragma unroll
    for (int t = 0; t < NTYPES; ++t) {
      const unsigned long long m = __ballot(sp == t);
      if ((tid & 63) == 0) wc[wv * NTYPES + t] = __popcll(m);
    }
    __syncthreads();
    if (tid < NTYPES)
      hist[tid * NBLK_H + blk] = wc[tid] + wc[4 + tid] + wc[8 + tid] + wc[12 + tid];
  }
}

// ---- scan + scatter (atomic-free counting sort, unchanged) ------------------

__global__ void k_scan(const int* __restrict__ hist, int* __restrict__ poff,
                       int* __restrict__ boff) {
  __shared__ int tot[NTYPES], base[NTYPES];
  const int tid = threadIdx.x, wv = tid >> 6, lane = tid & 63;
  int s = 0;
  for (int c = 0; c < 8; ++c) s += hist[wv * NBLK_H + c * 64 + lane];
  for (int off = 32; off; off >>= 1) s += __shfl_down(s, off);
  if (lane == 0) tot[wv] = s;
  __syncthreads();
  if (tid == 0) {
    int acc = 0; poff[0] = 0;
    for (int t = 0; t < NTYPES; ++t) {
      base[t] = acc;
      acc += ((tot[t] + 63) >> 6) << 6;
      poff[t + 1] = acc;
    }
  }
  __syncthreads();
  int carry = base[wv];
  for (int c = 0; c < 8; ++c) {
    const int orig = hist[wv * NBLK_H + c * 64 + lane];
    int v = orig;
    for (int off = 1; off < 64; off <<= 1) {
      const int u = __shfl_up(v, off);
      if (lane >= off) v += u;
    }
    boff[wv * NBLK_H + c * 64 + lane] = carry + v - orig;
    carry += __shfl(v, 63);
  }
}

__global__ void k_scatter(const int* __restrict__ species, const int* __restrict__ boff,
                          int* __restrict__ perm) {
  const int tid = threadIdx.x, blk = blockIdx.x;
  const int i = blk * 256 + tid;
  const int sp = species[i];
  const int wv = tid >> 6;
  __shared__ int wc[4 * NTYPES];
  unsigned long long msel = 0;
#pragma unroll
  for (int t = 0; t < NTYPES; ++t) {
    const unsigned long long m = __ballot(sp == t);
    if ((tid & 63) == 0) wc[wv * NTYPES + t] = __popcll(m);
    if (sp == t) msel = m;
  }
  __syncthreads();
  int woff = 0;
  for (int w = 0; w < wv; ++w) woff += wc[w * NTYPES + sp];
  const int rk = __builtin_amdgcn_mbcnt_hi((unsigned)(msel >> 32),
                 __builtin_amdgcn_mbcnt_lo((unsigned)msel, 0));
  perm[boff[sp * NBLK_H + blk] + woff + rk] = i;
}

// ---- fused 4-layer MFMA MLP + molecule reduction ----------------------------
// 256 threads = 4 waves; wave w = M-tile of 16 atoms. One LDS arena reused:
// X-slice 64x(96+8) -> H0 64x(160+8) -> H1 64x(128+8) -> H2 64x(96+8), all bf16.
// Strides 104/168/136: worst LDS bank aliasing 2-way (free, m136).

__global__ __launch_bounds__(256, 6) void k_mlp(
    const float* __restrict__ aev, const unsigned short* __restrict__ WB,
    const float* __restrict__ b0, const float* __restrict__ b1,
    const float* __restrict__ b2, const float* __restrict__ b3,
    const float* __restrict__ W3,
    const int* __restrict__ poff, const int* __restrict__ perm,
    float* __restrict__ outE)
{
  __shared__ __align__(16) unsigned short ARENA[64 * 168];   // 21504 B
  __shared__ float red[256];
  __shared__ int   permS[64];

  const int tid  = threadIdx.x;
  const int lane = tid & 63;
  const int wv   = __builtin_amdgcn_readfirstlane(tid >> 6);
  const int quad = lane >> 4, l15 = lane & 15;
  const int slot0 = blockIdx.x * MBLK;

  if (tid < 64) permS[tid] = perm[slot0 + tid];
  int t_ = (slot0 >= poff[1]) + (slot0 >= poff[2]) + (slot0 >= poff[3]);
  if (t_ > 3) t_ = 3;
  const int t = __builtin_amdgcn_readfirstlane(t_);
  __syncthreads();

  const bf16x8* wb0 = (const bf16x8*)(WB + (size_t)t * WB_T);
  const bf16x8* wb1 = (const bf16x8*)(WB + (size_t)t * WB_T + WB_L1);
  const bf16x8* wb2 = (const bf16x8*)(WB + (size_t)t * WB_T + WB_L2);

  // ---------------- layer 0: 384 -> 160, X staged in 4 slices of 96 ----------
  f32x4 acc0[10];
#pragma unroll
  for (int nt = 0; nt < 10; ++nt) {
    const float b = b0[t * 160 + nt * 16 + l15];
    acc0[nt] = (f32x4){b, b, b, b};
  }
  const int sm = tid >> 2, scg = tid & 3;          // staging: 4 threads/atom
  const int sai = permS[sm];
  const float4* src = (const float4*)(aev + (size_t)(sai < 0 ? 0 : sai) * AEV);
  for (int s = 0; s < 4; ++s) {
#pragma unroll
    for (int ii = 0; ii < 6; ++ii) {
      const int c4 = scg + ii * 4;                 // float4 index within slice
      float4 v = make_float4(0.f, 0.f, 0.f, 0.f);
      if (sai >= 0) v = src[s * 24 + c4];
      ushort4 p = {f2bf(v.x), f2bf(v.y), f2bf(v.z), f2bf(v.w)};
      *(ushort4*)&ARENA[sm * 104 + c4 * 4] = p;
    }
    __syncthreads();
    const int arow = (wv * 16 + l15) * 104 + quad * 8;
#pragma unroll
    for (int ks = 0; ks < 3; ++ks) {
      const bf16x8 a = *(const bf16x8*)&ARENA[arow + ks * 32];
      const int ksg = s * 3 + ks;
#pragma unroll
      for (int nt = 0; nt < 10; ++nt)
        acc0[nt] = __builtin_amdgcn_mfma_f32_16x16x32_bf16(a, wb0[(ksg * 10 + nt) * 64 + lane], acc0[nt], 0, 0, 0);
    }
    __syncthreads();
  }
  {
    const int hrow0 = wv * 16 + quad * 4;          // H0: stride 168
#pragma unroll
    for (int nt = 0; nt < 10; ++nt)
#pragma unroll
      for (int r = 0; r < 4; ++r)
        ARENA[(hrow0 + r) * 168 + nt * 16 + l15] = f2bf(celu01(acc0[nt][r]));
  }
  __syncthreads();

  // ---------------- layer 1: 160 -> 128 --------------------------------------
  f32x4 acc1[8];
#pragma unroll
  for (int nt = 0; nt < 8; ++nt) {
    const float b = b1[t * 128 + nt * 16 + l15];
    acc1[nt] = (f32x4){b, b, b, b};
  }
  {
    const int arow = (wv * 16 + l15) * 168 + quad * 8;
#pragma unroll
    for (int ks = 0; ks < 5; ++ks) {
      const bf16x8 a = *(const bf16x8*)&ARENA[arow + ks * 32];
#pragma unroll
      for (int nt = 0; nt < 8; ++nt)
        acc1[nt] = __builtin_amdgcn_mfma_f32_16x16x32_bf16(a, wb1[(ks * 8 + nt) * 64 + lane], acc1[nt], 0, 0, 0);
    }
  }
  __syncthreads();                                  // all H0 reads done
  {
    const int hrow0 = wv * 16 + quad * 4;          // H1: stride 136
#pragma unroll
    for (int nt = 0; nt < 8; ++nt)
#pragma unroll
      for (int r = 0; r < 4; ++r)
        ARENA[(hrow0 + r) * 136 + nt * 16 + l15] = f2bf(celu01(acc1[nt][r]));
  }
  __syncthreads();

  // ---------------- layer 2: 128 -> 96 ---------------------------------------
  f32x4 acc2[6];
#pragma unroll
  for (int nt = 0; nt < 6; ++nt) {
    const float b = b2[t * 96 + nt * 16 + l15];
    acc2[nt] = (f32x4){b, b, b, b};
  }
  {
    const int arow = (wv * 16 + l15) * 136 + quad * 8;
#pragma unroll
    for (int ks = 0; ks < 4; ++ks) {
      const bf16x8 a = *(const bf16x8*)&ARENA[arow + ks * 32];
#pragma unroll
      for (int nt = 0; nt < 6; ++nt)
        acc2[nt] = __builtin_amdgcn_mfma_f32_16x16x32_bf16(a, wb2[(ks * 6 + nt) * 64 + lane], acc2[nt], 0, 0, 0);
    }
  }
  __syncthreads();                                  // all H1 reads done
  {
    const int hrow0 = wv * 16 + quad * 4;          // H2: stride 104
#pragma unroll
    for (int nt = 0; nt < 6; ++nt)
#pragma unroll
      for (int r = 0; r < 4; ++r)
        ARENA[(hrow0 + r) * 104 + nt * 16 + l15] = f2bf(celu01(acc2[nt][r]));
  }
  __syncthreads();

  // ---------------- layer 3: 96 -> 1, molecule reduce ------------------------
  const float* w3 = W3 + t * 96;
  float part = 0.f;
#pragma unroll
  for (int q = 0; q < 24; ++q) {
    const int c = wv * 24 + q;                     // wave-uniform -> s_load
    part = fmaf(bf2f(ARENA[lane * 104 + c]), w3[c], part);
  }
  red[wv * 64 + lane] = part;
  __syncthreads();
  if (wv == 0) {
    const float e = red[lane] + red[64 + lane] + red[128 + lane] + red[192 + lane] + b3[t];
    const int ai = permS[lane];
    if (ai >= 0) atomicAdd(&outE[ai >> 6], e);
  }
}

// ---- launch -----------------------------------------------------------------

extern "C" void kernel_launch(void* const* d_in, const int* in_sizes, int n_in,
                              void* d_out, int out_size, void* d_ws, size_t ws_size,
                              hipStream_t stream)
{
  const int*   species = (const int*)d_in[0];
  const float* aev     = (const float*)d_in[1];
  const float* W0 = (const float*)d_in[2];
  const float* b0 = (const float*)d_in[3];
  const float* W1 = (const float*)d_in[4];
  const float* b1 = (const float*)d_in[5];
  const float* W2 = (const float*)d_in[6];
  const float* b2 = (const float*)d_in[7];
  const float* W3 = (const float*)d_in[8];
  const float* b3 = (const float*)d_in[9];
  float* out = (float*)d_out;

  // ws (ints): poff[8], hist[2048], boff[2048], perm[PADTOT]; then bf16 WB
  int* poff = (int*)d_ws;
  int* hist = poff + 8;
  int* boff = hist + NTYPES * NBLK_H;
  int* perm = boff + NTYPES * NBLK_H;
  unsigned short* WB = (unsigned short*)(perm + PADTOT);

  k_pre    <<<PADTOT / 256, 256, 0, stream>>>(species, out, perm, hist, W0, W1, W2, WB);
  k_scan   <<<1, 256, 0, stream>>>(hist, poff, boff);
  k_scatter<<<NBLK_H, 256, 0, stream>>>(species, boff, perm);
  k_mlp    <<<NBLK_MLP, 256, 0, stream>>>(aev, WB, b0, b1, b2, b3, W3,
                                          poff, perm, out + NATOMS);
}